// Round 13
// baseline (148.207 us; speedup 1.0000x reference)
//
#include <hip/hip_runtime.h>

#define Bn 8
#define Hn 8
#define Tn 1024
#define Dn 128

typedef __attribute__((ext_vector_type(8))) short bf16x8;
typedef __attribute__((ext_vector_type(4))) float f32x4;

typedef __attribute__((address_space(3))) unsigned int lds_as_t;
typedef __attribute__((address_space(1))) const unsigned int glb_as_t;

static __device__ __forceinline__ void gload_lds16(const unsigned short* g, unsigned short* l) {
    __builtin_amdgcn_global_load_lds((glb_as_t*)g, (lds_as_t*)l, 16, 0, 0);
}
static __device__ __forceinline__ void gload_lds16b(const char* g, char* l) {
    __builtin_amdgcn_global_load_lds((glb_as_t*)g, (lds_as_t*)l, 16, 0, 0);
}

static __device__ __forceinline__ unsigned short f2bf(float f) {
    union { float f; unsigned int u; } v; v.f = f;
    unsigned int u = v.u;
    return (unsigned short)((u + 0x7FFFu + ((u >> 16) & 1u)) >> 16);
}
// truncating bf16 pack via byte-perm: result = [hi>>16, lo>>16]
static __device__ __forceinline__ int pack_bf16_trunc(float lo, float hi) {
    union { float f; unsigned int u; } a, b;
    a.f = lo; b.f = hi;
    return (int)__builtin_amdgcn_perm(b.u, a.u, 0x07060302u);
}

// ---------------- prep: converts + wuF per-head fragment reorder + mask bits + bias preset ----------------
__global__ __launch_bounds__(256) void prep_kernel(
    const float* __restrict__ x,  const float* __restrict__ Wq,
    const float* __restrict__ Wk, const float* __restrict__ Wv,
    const float* __restrict__ Wu, const int* __restrict__ mask,
    const float* __restrict__ bu, float* __restrict__ outp,
    unsigned short* __restrict__ xb,  unsigned short* __restrict__ wqB,
    unsigned short* __restrict__ wkB, unsigned short* __restrict__ wvB,
    unsigned short* __restrict__ wuF, unsigned long long* __restrict__ bits)
{
    const int blk = blockIdx.x;
    const int tid = threadIdx.x;

    if (blk < 1408) {  // swizzled converts (16B chunk c ^= row&15)
        const float* in; unsigned short* out; int i4;
        if (blk < 1024)      { in = x;  out = xb;  i4 = blk * 256 + tid; }
        else if (blk < 1152) { in = Wq; out = wqB; i4 = (blk - 1024) * 256 + tid; }
        else if (blk < 1280) { in = Wk; out = wkB; i4 = (blk - 1152) * 256 + tid; }
        else                 { in = Wv; out = wvB; i4 = (blk - 1280) * 256 + tid; }
        float4 f = ((const float4*)in)[i4];
        ushort4 o;
        o.x = f2bf(f.x); o.y = f2bf(f.y); o.z = f2bf(f.z); o.w = f2bf(f.w);
        int base = i4 * 4;
        int row = base >> 7, col = base & 127;
        int scol = (((col >> 3) ^ (row & 15)) << 3) | (col & 7);
        *(ushort4*)(out + row * 128 + scol) = o;
    } else if (blk < 1536) {  // Wu -> per-head fragment-major
        if (tid < 128) {
            int id = (blk - 1408) * 128 + tid;
            int lane_ = id & 63;
            int fid = id >> 6;                   // ((h*4+ks)*8+nt)
            int nt = fid & 7, ks = (fid >> 3) & 3, h = fid >> 5;
            int row = nt * 16 + (lane_ & 15);
            int col = h * 128 + ks * 32 + (lane_ >> 4) * 8;
            const float* src = Wu + (size_t)row * 1024 + col;
            float4 f0 = *(const float4*)(src);
            float4 f1 = *(const float4*)(src + 4);
            unsigned short o[8];
            o[0] = f2bf(f0.x); o[1] = f2bf(f0.y); o[2] = f2bf(f0.z); o[3] = f2bf(f0.w);
            o[4] = f2bf(f1.x); o[5] = f2bf(f1.y); o[6] = f2bf(f1.z); o[7] = f2bf(f1.w);
            *(ushort4*)(wuF + (size_t)id * 8)     = *(ushort4*)&o[0];
            *(ushort4*)(wuF + (size_t)id * 8 + 4) = *(ushort4*)&o[4];
        }
    } else if (blk < 2560) {  // maskbits, TRANSPOSED: bits[kt*1024 + row]
        int wid  = (blk - 1536) * 4 + (tid >> 6);
        int lane = tid & 63;
#pragma unroll
        for (int i = 0; i < 4; i++) {
            int widx = wid * 4 + i;
            int row = widx >> 4, kt = widx & 15;
            int v = mask[row * Tn + kt * 64 + lane];
            unsigned long long b = __ballot(v != 0);
            if (lane == 0) bits[kt * Tn + row] = b;
        }
    } else {  // out preset = bias
        int f4 = (blk - 2560) * 1024 + tid * 4;
#pragma unroll
        for (int i = 0; i < 4; i++)
            ((float4*)outp)[f4 + i] = ((const float4*)bu)[(f4 + i) & 31];
    }
}

// ---------------- fused QKV GEMM: one block = (m-tile, head), computes Q,K,V ----------------
// grid (64, 8). A-tile staged ONCE; wq/wk/wv slices staged pipelined (wk during Q compute,
// wv during K compute). LDS: A 32K + B 3x32K + escr 18.4K = 146.4 KB -> 1 block/CU.
// Epilogues identical to R12: Q/K fp8 via LDS transpose, V bf16 direct tiled.
__global__ __launch_bounds__(256, 1) void qkv_kernel(
    const unsigned short* __restrict__ xb,   // [8192][128] swizzled bf16
    const unsigned short* __restrict__ wqB,  // [1024][128] swizzled bf16
    const unsigned short* __restrict__ wkB,
    const unsigned short* __restrict__ wvB,
    char* __restrict__ Q,
    char* __restrict__ K,
    unsigned short* __restrict__ Vt)
{
    const int bx = blockIdx.x, by = blockIdx.y;   // m-tile, head
    const int wave = threadIdx.x >> 6;
    const int lane = threadIdx.x & 63;
    const int l16  = lane & 15;
    const int quad = lane >> 4;
    const int wm = wave & 1, wn = wave >> 1;

    __shared__ __align__(16) unsigned short As[128 * 128];       // 32 KB
    __shared__ __align__(16) unsigned short Bs[3][128 * 128];    // 96 KB
    __shared__ __align__(16) char escr[128 * 144];               // 18.4 KB

    const unsigned short* Ag = xb + (size_t)bx * 128 * 128;
    const unsigned short* Bg0 = wqB + (size_t)by * 128 * 128;
    const unsigned short* Bg1 = wkB + (size_t)by * 128 * 128;
    const unsigned short* Bg2 = wvB + (size_t)by * 128 * 128;

    // stage A + wq
#pragma unroll
    for (int i = 0; i < 8; i++) {
        int base = (wave * 8 + i) * 512;
        gload_lds16(Ag  + base + lane * 8, &As[base]);
        gload_lds16(Bg0 + base + lane * 8, &Bs[0][base]);
    }
    __syncthreads();

    // A fragments once (reused for all three matrices)
    bf16x8 a[4][4];
#pragma unroll
    for (int mt = 0; mt < 4; mt++) {
        int row = wm * 64 + mt * 16 + l16;
#pragma unroll
        for (int ks = 0; ks < 4; ks++)
            a[mt][ks] = *(const bf16x8*)(&As[row * 128 + (((ks * 4 + quad) ^ (row & 15)) << 3)]);
    }

    const int h_ = by;
    const int b_ = bx >> 3;
    f32x4 acc[4][4];

    // ================= Q =================
    {
        // issue wk staging (overlaps Q compute)
#pragma unroll
        for (int i = 0; i < 8; i++) {
            int base = (wave * 8 + i) * 512;
            gload_lds16(Bg1 + base + lane * 8, &Bs[1][base]);
        }
#pragma unroll
        for (int nt = 0; nt < 4; nt++) {
            int row = wn * 64 + nt * 16 + l16;
            bf16x8 b4[4];
#pragma unroll
            for (int ks = 0; ks < 4; ks++)
                b4[ks] = *(const bf16x8*)(&Bs[0][row * 128 + (((ks * 4 + quad) ^ (row & 15)) << 3)]);
#pragma unroll
            for (int mt = 0; mt < 4; mt++) {
                f32x4 c = {0.f, 0.f, 0.f, 0.f};
#pragma unroll
                for (int ks = 0; ks < 4; ks++)
                    c = __builtin_amdgcn_mfma_f32_16x16x32_bf16(a[mt][ks], b4[ks], c, 0, 0, 0);
                acc[mt][nt] = c;
            }
        }
        // fp8 -> escr
#pragma unroll
        for (int mt = 0; mt < 4; mt++) {
#pragma unroll
            for (int nt = 0; nt < 4; nt++) {
                int w = __builtin_amdgcn_cvt_pk_fp8_f32(acc[mt][nt][0], acc[mt][nt][1], 0, false);
                w = __builtin_amdgcn_cvt_pk_fp8_f32(acc[mt][nt][2], acc[mt][nt][3], w, true);
                int col = wn * 64 + nt * 16 + l16;
#pragma unroll
                for (int r = 0; r < 4; r++)
                    escr[(wm * 64 + mt * 16 + quad * 4 + r) * 144 + col] = (char)(w >> (8 * r));
            }
        }
        __syncthreads();   // escr visible; wk staged
        const int f = threadIdx.x;
        int row = f >> 1;
        int t_in = (bx & 7) * 128 + row;
        size_t rowbase = ((size_t)((b_ * Hn + h_) * Tn + t_in)) * 128;
#pragma unroll
        for (int i = 0; i < 4; i++) {
            int c = (f & 1) * 4 + i;
            int4 v = *(const int4*)(escr + row * 144 + c * 16);
            *(int4*)(Q + rowbase + c * 16) = v;
        }
    }

    // ================= K =================
    {
        // issue wv staging (overlaps K compute)
#pragma unroll
        for (int i = 0; i < 8; i++) {
            int base = (wave * 8 + i) * 512;
            gload_lds16(Bg2 + base + lane * 8, &Bs[2][base]);
        }
#pragma unroll
        for (int nt = 0; nt < 4; nt++) {
            int row = wn * 64 + nt * 16 + l16;
            bf16x8 b4[4];
#pragma unroll
            for (int ks = 0; ks < 4; ks++)
                b4[ks] = *(const bf16x8*)(&Bs[1][row * 128 + (((ks * 4 + quad) ^ (row & 15)) << 3)]);
#pragma unroll
            for (int mt = 0; mt < 4; mt++) {
                f32x4 c = {0.f, 0.f, 0.f, 0.f};
#pragma unroll
                for (int ks = 0; ks < 4; ks++)
                    c = __builtin_amdgcn_mfma_f32_16x16x32_bf16(a[mt][ks], b4[ks], c, 0, 0, 0);
                acc[mt][nt] = c;
            }
        }
        __syncthreads();   // all Q escr reads done; wv staged
#pragma unroll
        for (int mt = 0; mt < 4; mt++) {
#pragma unroll
            for (int nt = 0; nt < 4; nt++) {
                int w = __builtin_amdgcn_cvt_pk_fp8_f32(acc[mt][nt][0], acc[mt][nt][1], 0, false);
                w = __builtin_amdgcn_cvt_pk_fp8_f32(acc[mt][nt][2], acc[mt][nt][3], w, true);
                int col = wn * 64 + nt * 16 + l16;
#pragma unroll
                for (int r = 0; r < 4; r++)
                    escr[(wm * 64 + mt * 16 + quad * 4 + r) * 144 + col] = (char)(w >> (8 * r));
            }
        }
        __syncthreads();   // escr (K) visible
        const int f = threadIdx.x;
        int row = f >> 1;
        int t_in = (bx & 7) * 128 + row;
        size_t rowbase = ((size_t)((b_ * Hn + h_) * Tn + t_in)) * 128;
#pragma unroll
        for (int i = 0; i < 4; i++) {
            int c = (f & 1) * 4 + i;
            int4 v = *(const int4*)(escr + row * 144 + c * 16);
            int cc = c ^ (row & 7);
            *(int4*)(K + rowbase + cc * 16) = v;
        }
    }

    // ================= V =================
    {
#pragma unroll
        for (int nt = 0; nt < 4; nt++) {
            int row = wn * 64 + nt * 16 + l16;
            bf16x8 b4[4];
#pragma unroll
            for (int ks = 0; ks < 4; ks++)
                b4[ks] = *(const bf16x8*)(&Bs[2][row * 128 + (((ks * 4 + quad) ^ (row & 15)) << 3)]);
#pragma unroll
            for (int mt = 0; mt < 4; mt++) {
                f32x4 c = {0.f, 0.f, 0.f, 0.f};
#pragma unroll
                for (int ks = 0; ks < 4; ks++)
                    c = __builtin_amdgcn_mfma_f32_16x16x32_bf16(a[mt][ks], b4[ks], c, 0, 0, 0);
                acc[mt][nt] = c;
            }
        }
#pragma unroll
        for (int mt = 0; mt < 4; mt++) {
            int m_base = bx * 128 + wm * 64 + mt * 16 + quad * 4;
            int t0 = m_base & 1023;
#pragma unroll
            for (int nt = 0; nt < 4; nt++) {
                int e_ = wn * 64 + nt * 16 + l16;
                int kt_ = t0 >> 6, tc0 = t0 & 63;
                size_t off = ((((size_t)(b_ * Hn + h_) * 16 + kt_) * 128 + e_) << 6)
                           + ((((tc0 >> 3) ^ (e_ & 7)) << 3) | (tc0 & 7));
                ushort4 v4;
                v4.x = f2bf(acc[mt][nt][0]); v4.y = f2bf(acc[mt][nt][1]);
                v4.z = f2bf(acc[mt][nt][2]); v4.w = f2bf(acc[mt][nt][3]);
                *(ushort4*)(Vt + off) = v4;
            }
        }
    }
}

// ---------------- flash attention + fused output projection (unchanged from R12) ----------------
__global__ __launch_bounds__(256, 3) void attn_kernel(
    const char* __restrict__ Q,               // fp8 [64][1024][128] plain
    const char* __restrict__ K,               // fp8 [64][1024][128] chunk swizzle c^(t&7)
    const unsigned short* __restrict__ Vt,    // bf16 [64][16][128][64] tiled+swizzled
    const unsigned long long* __restrict__ mbits, // [16][1024] transposed
    const unsigned short* __restrict__ wuF,   // [((h*4+ks)*8+nt)*64+lane][8]
    float* __restrict__ out)                  // [8192][128] fp32, bias-preset
{
    const int qt   = 15 - ((blockIdx.x + blockIdx.y) & 15);
    const int bh   = blockIdx.y;
    const int wave = threadIdx.x >> 6;
    const int lane = threadIdx.x & 63;
    const int l16  = lane & 15;
    const int quad = lane >> 4;

    __shared__ __align__(16) char kbuf[2][64 * 128];            // 8 KB each
    __shared__ __align__(16) unsigned short vbuf[2][128 * 64];  // 16 KB each

    const char* Qb = Q  + (size_t)bh * Tn * Dn;
    const char* Kb = K  + (size_t)bh * Tn * Dn;
    const unsigned short* Vb = Vt + (size_t)bh * (16 * 128 * 64);

    const int q0 = qt * 64 + wave * 16;
    const int qrow = q0 + quad * 4;

    long qf[4];
#pragma unroll
    for (int ks = 0; ks < 4; ks++)
        qf[ks] = *(const long*)(Qb + (size_t)(q0 + l16) * 128 + ks * 32 + quad * 8);

    bf16x8 ones;
#pragma unroll
    for (int j = 0; j < 8; j++) ones[j] = (short)0x3F80;

    f32x4 o[8];
#pragma unroll
    for (int et = 0; et < 8; et++) o[et] = (f32x4){0.f, 0.f, 0.f, 0.f};
    f32x4 lacc = {0.f, 0.f, 0.f, 0.f};

    const float SL = 0.12752041570284543f;  // 1/sqrt(128) * log2(e)

    const int idx0 = (l16 << 2) + ((quad & 1) << 7);
    const int idx1 = idx0 + 64;
    const bool hiQ = (quad >> 1) != 0;

    // prologue staging
#pragma unroll
    for (int i = 0; i < 2; i++) {
        int base = (wave * 2 + i) * 1024;
        gload_lds16b(Kb + base + lane * 16, &kbuf[0][base]);
    }
#pragma unroll
    for (int i = 0; i < 4; i++) {
        int base = (wave * 4 + i) * 512;
        gload_lds16(Vb + base + lane * 8, &vbuf[0][base]);
    }

    for (int kt = 0; kt <= qt; kt++) {
        const int cur = kt & 1;
        __syncthreads();

        if (kt < qt) {
            const char* Kg = Kb + (kt + 1) * (64 * 128);
            const unsigned short* Vg = Vb + (kt + 1) * (128 * 64);
#pragma unroll
            for (int i = 0; i < 2; i++) {
                int base = (wave * 2 + i) * 1024;
                gload_lds16b(Kg + base + lane * 16, &kbuf[cur ^ 1][base]);
            }
#pragma unroll
            for (int i = 0; i < 4; i++) {
                int base = (wave * 4 + i) * 512;
                gload_lds16(Vg + base + lane * 8, &vbuf[cur ^ 1][base]);
            }
        }

        const unsigned long long mw = mbits[kt * Tn + q0 + l16];

        // S^T = K·Q^T (fp8)
        f32x4 s[4];
#pragma unroll
        for (int nt = 0; nt < 4; nt++) {
            int row = nt * 16 + l16;
            long a4[4];
#pragma unroll
            for (int ks = 0; ks < 4; ks++) {
                int c = ks * 2 + (quad >> 1);
                a4[ks] = *(const long*)(&kbuf[cur][row * 128 + (((c ^ (row & 7)) << 4) | ((quad & 1) << 3))]);
            }
            f32x4 c = {0.f, 0.f, 0.f, 0.f};
#pragma unroll
            for (int ks = 0; ks < 4; ks++)
                c = __builtin_amdgcn_mfma_f32_16x16x32_fp8_fp8(a4[ks], qf[ks], c, 0, 0, 0);
            s[nt] = c;
        }

        // p = live ? exp2(s*SL) : 0, packed (truncating) to bf16 pairs
        const int kc0 = kt * 64;
        const int qglob = q0 + l16;
        int w[4][2];
#pragma unroll
        for (int nt = 0; nt < 4; nt++) {
            float pv[4];
#pragma unroll
            for (int r = 0; r < 4; r++) {
                int bit = nt * 16 + quad * 4 + r;
                bool live = ((mw >> bit) & 1ULL) && (kc0 + bit <= qglob);
                pv[r] = live ? __builtin_amdgcn_exp2f(s[nt][r] * SL) : 0.f;
            }
            w[nt][0] = pack_bf16_trunc(pv[0], pv[1]);
            w[nt][1] = pack_bf16_trunc(pv[2], pv[3]);
        }

        bf16x8 pf[2];
#pragma unroll
        for (int k2 = 0; k2 < 2; k2++) {
            union { int i[4]; bf16x8 v; } u;
#pragma unroll
            for (int d = 0; d < 4; d++) {
                int idx = (d < 2) ? idx0 : idx1;
                int va = __builtin_amdgcn_ds_bpermute(idx, w[2 * k2][d & 1]);
                int vb = __builtin_amdgcn_ds_bpermute(idx, w[2 * k2 + 1][d & 1]);
                u.i[d] = hiQ ? vb : va;
            }
            pf[k2] = u.v;
        }

#pragma unroll
        for (int k2 = 0; k2 < 2; k2++)
            lacc = __builtin_amdgcn_mfma_f32_16x16x32_bf16(pf[k2], ones, lacc, 0, 0, 0);

#pragma unroll
        for (int et = 0; et < 8; et++) {
            int row = et * 16 + l16;
#pragma unroll
            for (int k2 = 0; k2 < 2; k2++) {
                bf16x8 b = *(const bf16x8*)(&vbuf[cur][row * 64 + (((k2 * 4 + quad) ^ (l16 & 7)) << 3)]);
                o[et] = __builtin_amdgcn_mfma_f32_16x16x32_bf16(pf[k2], b, o[et], 0, 0, 0);
            }
        }
    }

    // phase 2: degenerate rows (l == 0) attend uniformly over all mask==0 keys
    __syncthreads();
    {
        bool deg = (lacc[0] == 0.f) | (lacc[1] == 0.f) | (lacc[2] == 0.f) | (lacc[3] == 0.f);
        if (__ballot(deg) != 0ULL) {
            unsigned short* pb = (unsigned short*)((char*)kbuf + wave * 2304);  // 16 x 72 shorts
            unsigned short dsel[4];
#pragma unroll
            for (int r = 0; r < 4; r++) dsel[r] = (lacc[r] == 0.f) ? (unsigned short)0x3F80 : (unsigned short)0;
            for (int kt = 0; kt < 16; kt++) {
                unsigned long long mw2[4];
#pragma unroll
                for (int r = 0; r < 4; r++) mw2[r] = mbits[kt * Tn + qrow + r];
#pragma unroll
                for (int nt = 0; nt < 4; nt++) {
                    int bi = nt * 16 + l16;
#pragma unroll
                    for (int r = 0; r < 4; r++)
                        pb[(quad * 4 + r) * 72 + bi] = ((mw2[r] >> bi) & 1ULL) ? (unsigned short)0 : dsel[r];
                }
                bf16x8 pf[2];
#pragma unroll
                for (int k2 = 0; k2 < 2; k2++)
                    pf[k2] = *(const bf16x8*)(&pb[l16 * 72 + k2 * 32 + quad * 8]);
#pragma unroll
                for (int k2 = 0; k2 < 2; k2++)
                    lacc = __builtin_amdgcn_mfma_f32_16x16x32_bf16(pf[k2], ones, lacc, 0, 0, 0);
                const unsigned short* Vg = Vb + kt * (128 * 64);
#pragma unroll
                for (int et = 0; et < 8; et++) {
#pragma unroll
                    for (int k2 = 0; k2 < 2; k2++) {
                        bf16x8 b = *(const bf16x8*)(Vg + (et * 16 + l16) * 64 + (((k2 * 4 + quad) ^ (l16 & 7)) << 3));
                        o[et] = __builtin_amdgcn_mfma_f32_16x16x32_bf16(pf[k2], b, o[et], 0, 0, 0);
                    }
                }
            }
        }
    }

    // ---- fused output projection epilogue ----
    const int b_ = bh >> 3, h_ = bh & 7;
    {
        unsigned short* tile = (unsigned short*)((char*)vbuf + wave * 4608);  // 16 rows x 144 shorts
#pragma unroll
        for (int r = 0; r < 4; r++) {
            float inv = 1.f / lacc[r];
            int row = quad * 4 + r;
#pragma unroll
            for (int et = 0; et < 8; et++)
                tile[row * 144 + et * 16 + l16] = f2bf(o[et][r] * inv);
        }

        bf16x8 a4[4];
#pragma unroll
        for (int ks = 0; ks < 4; ks++)
            a4[ks] = *(const bf16x8*)(&tile[l16 * 144 + ks * 32 + quad * 8]);

        const unsigned short* wf = wuF + (size_t)h_ * (4 * 8 * 64 * 8);
        f32x4 acc2[8];
#pragma unroll
        for (int nt = 0; nt < 8; nt++) acc2[nt] = (f32x4){0.f, 0.f, 0.f, 0.f};
#pragma unroll
        for (int ks = 0; ks < 4; ks++) {
#pragma unroll
            for (int nt = 0; nt < 8; nt++) {
                bf16x8 b = *(const bf16x8*)(wf + ((size_t)(ks * 8 + nt) * 64 + lane) * 8);
                acc2[nt] = __builtin_amdgcn_mfma_f32_16x16x32_bf16(a4[ks], b, acc2[nt], 0, 0, 0);
            }
        }

#pragma unroll
        for (int nt = 0; nt < 8; nt++) {
            int n = nt * 16 + l16;
#pragma unroll
            for (int r = 0; r < 4; r++) {
                int q = q0 + quad * 4 + r;
                atomicAdd(&out[(size_t)(b_ * Tn + q) * Dn + n], acc2[nt][r]);
            }
        }
    }
}

extern "C" void kernel_launch(void* const* d_in, const int* in_sizes, int n_in,
                              void* d_out, int out_size, void* d_ws, size_t ws_size,
                              hipStream_t stream) {
    const float* x   = (const float*)d_in[0];
    const int* mask  = (const int*)d_in[1];
    const float* Wk  = (const float*)d_in[2];
    const float* Wq  = (const float*)d_in[3];
    const float* Wv  = (const float*)d_in[4];
    const float* Wu  = (const float*)d_in[5];
    const float* bu  = (const float*)d_in[6];
    float* out = (float*)d_out;

    char* ws = (char*)d_ws;
    unsigned short* xb  = (unsigned short*)ws; ws += (size_t)8192 * 128 * 2;
    unsigned short* wqB = (unsigned short*)ws; ws += (size_t)1024 * 128 * 2;
    unsigned short* wkB = (unsigned short*)ws; ws += (size_t)1024 * 128 * 2;
    unsigned short* wvB = (unsigned short*)ws; ws += (size_t)1024 * 128 * 2;
    unsigned short* wuF = (unsigned short*)ws; ws += (size_t)128 * 1024 * 2;
    char* Qf  = ws; ws += (size_t)64 * 1024 * 128;
    char* Kf  = ws; ws += (size_t)64 * 1024 * 128;
    unsigned short* Vtw = (unsigned short*)ws; ws += (size_t)64 * 1024 * 128 * 2;
    unsigned long long* mb = (unsigned long long*)ws; ws += (size_t)1024 * 16 * 8;

    prep_kernel<<<dim3(2816), 256, 0, stream>>>(x, Wq, Wk, Wv, Wu, mask, bu, out,
                                                xb, wqB, wkB, wvB, wuF, mb);
    qkv_kernel<<<dim3(64, 8), 256, 0, stream>>>(xb, wqB, wkB, wvB, Qf, Kf, Vtw);
    attn_kernel<<<dim3(16, 64), 256, 0, stream>>>(Qf, Kf, Vtw, mb, wuF, out);
}

// Round 14
// 147.708 us; speedup vs baseline: 1.0034x; 1.0034x over previous
//
#include <hip/hip_runtime.h>

#define Bn 8
#define Hn 8
#define Tn 1024
#define Dn 128

typedef __attribute__((ext_vector_type(8))) short bf16x8;
typedef __attribute__((ext_vector_type(4))) float f32x4;

typedef __attribute__((address_space(3))) unsigned int lds_as_t;
typedef __attribute__((address_space(1))) const unsigned int glb_as_t;

static __device__ __forceinline__ void gload_lds16(const unsigned short* g, unsigned short* l) {
    __builtin_amdgcn_global_load_lds((glb_as_t*)g, (lds_as_t*)l, 16, 0, 0);
}
static __device__ __forceinline__ void gload_lds16b(const char* g, char* l) {
    __builtin_amdgcn_global_load_lds((glb_as_t*)g, (lds_as_t*)l, 16, 0, 0);
}

static __device__ __forceinline__ unsigned short f2bf(float f) {
    union { float f; unsigned int u; } v; v.f = f;
    unsigned int u = v.u;
    return (unsigned short)((u + 0x7FFFu + ((u >> 16) & 1u)) >> 16);
}
// truncating bf16 pack via byte-perm: result = [hi>>16, lo>>16]
static __device__ __forceinline__ int pack_bf16_trunc(float lo, float hi) {
    union { float f; unsigned int u; } a, b;
    a.f = lo; b.f = hi;
    return (int)__builtin_amdgcn_perm(b.u, a.u, 0x07060302u);
}

// ---------------- prep: converts + wuF per-head fragment reorder + mask bits + bias preset ----------------
__global__ __launch_bounds__(256) void prep_kernel(
    const float* __restrict__ x,  const float* __restrict__ Wq,
    const float* __restrict__ Wk, const float* __restrict__ Wv,
    const float* __restrict__ Wu, const int* __restrict__ mask,
    const float* __restrict__ bu, float* __restrict__ outp,
    unsigned short* __restrict__ xb,  unsigned short* __restrict__ wqB,
    unsigned short* __restrict__ wkB, unsigned short* __restrict__ wvB,
    unsigned short* __restrict__ wuF, unsigned long long* __restrict__ bits)
{
    const int blk = blockIdx.x;
    const int tid = threadIdx.x;

    if (blk < 1408) {  // swizzled converts (16B chunk c ^= row&15)
        const float* in; unsigned short* out; int i4;
        if (blk < 1024)      { in = x;  out = xb;  i4 = blk * 256 + tid; }
        else if (blk < 1152) { in = Wq; out = wqB; i4 = (blk - 1024) * 256 + tid; }
        else if (blk < 1280) { in = Wk; out = wkB; i4 = (blk - 1152) * 256 + tid; }
        else                 { in = Wv; out = wvB; i4 = (blk - 1280) * 256 + tid; }
        float4 f = ((const float4*)in)[i4];
        ushort4 o;
        o.x = f2bf(f.x); o.y = f2bf(f.y); o.z = f2bf(f.z); o.w = f2bf(f.w);
        int base = i4 * 4;
        int row = base >> 7, col = base & 127;
        int scol = (((col >> 3) ^ (row & 15)) << 3) | (col & 7);
        *(ushort4*)(out + row * 128 + scol) = o;
    } else if (blk < 1536) {  // Wu -> per-head fragment-major
        if (tid < 128) {
            int id = (blk - 1408) * 128 + tid;
            int lane_ = id & 63;
            int fid = id >> 6;                   // ((h*4+ks)*8+nt)
            int nt = fid & 7, ks = (fid >> 3) & 3, h = fid >> 5;
            int row = nt * 16 + (lane_ & 15);
            int col = h * 128 + ks * 32 + (lane_ >> 4) * 8;
            const float* src = Wu + (size_t)row * 1024 + col;
            float4 f0 = *(const float4*)(src);
            float4 f1 = *(const float4*)(src + 4);
            unsigned short o[8];
            o[0] = f2bf(f0.x); o[1] = f2bf(f0.y); o[2] = f2bf(f0.z); o[3] = f2bf(f0.w);
            o[4] = f2bf(f1.x); o[5] = f2bf(f1.y); o[6] = f2bf(f1.z); o[7] = f2bf(f1.w);
            *(ushort4*)(wuF + (size_t)id * 8)     = *(ushort4*)&o[0];
            *(ushort4*)(wuF + (size_t)id * 8 + 4) = *(ushort4*)&o[4];
        }
    } else if (blk < 2560) {  // maskbits, TRANSPOSED: bits[kt*1024 + row]
        int wid  = (blk - 1536) * 4 + (tid >> 6);
        int lane = tid & 63;
#pragma unroll
        for (int i = 0; i < 4; i++) {
            int widx = wid * 4 + i;
            int row = widx >> 4, kt = widx & 15;
            int v = mask[row * Tn + kt * 64 + lane];
            unsigned long long b = __ballot(v != 0);
            if (lane == 0) bits[kt * Tn + row] = b;
        }
    } else {  // out preset = bias
        int f4 = (blk - 2560) * 1024 + tid * 4;
#pragma unroll
        for (int i = 0; i < 4; i++)
            ((float4*)outp)[f4 + i] = ((const float4*)bu)[(f4 + i) & 31];
    }
}

// ---------------- fused QKV GEMM: one block = (m-tile, head), computes Q,K,V ----------------
__global__ __launch_bounds__(256, 1) void qkv_kernel(
    const unsigned short* __restrict__ xb,   // [8192][128] swizzled bf16
    const unsigned short* __restrict__ wqB,  // [1024][128] swizzled bf16
    const unsigned short* __restrict__ wkB,
    const unsigned short* __restrict__ wvB,
    char* __restrict__ Q,
    char* __restrict__ K,
    unsigned short* __restrict__ Vt)
{
    const int bx = blockIdx.x, by = blockIdx.y;   // m-tile, head
    const int wave = threadIdx.x >> 6;
    const int lane = threadIdx.x & 63;
    const int l16  = lane & 15;
    const int quad = lane >> 4;
    const int wm = wave & 1, wn = wave >> 1;

    __shared__ __align__(16) unsigned short As[128 * 128];       // 32 KB
    __shared__ __align__(16) unsigned short Bs[3][128 * 128];    // 96 KB
    __shared__ __align__(16) char escr[128 * 144];               // 18.4 KB

    const unsigned short* Ag = xb + (size_t)bx * 128 * 128;
    const unsigned short* Bg0 = wqB + (size_t)by * 128 * 128;
    const unsigned short* Bg1 = wkB + (size_t)by * 128 * 128;
    const unsigned short* Bg2 = wvB + (size_t)by * 128 * 128;

#pragma unroll
    for (int i = 0; i < 8; i++) {
        int base = (wave * 8 + i) * 512;
        gload_lds16(Ag  + base + lane * 8, &As[base]);
        gload_lds16(Bg0 + base + lane * 8, &Bs[0][base]);
    }
    __syncthreads();

    bf16x8 a[4][4];
#pragma unroll
    for (int mt = 0; mt < 4; mt++) {
        int row = wm * 64 + mt * 16 + l16;
#pragma unroll
        for (int ks = 0; ks < 4; ks++)
            a[mt][ks] = *(const bf16x8*)(&As[row * 128 + (((ks * 4 + quad) ^ (row & 15)) << 3)]);
    }

    const int h_ = by;
    const int b_ = bx >> 3;
    f32x4 acc[4][4];

    // ================= Q =================
    {
#pragma unroll
        for (int i = 0; i < 8; i++) {
            int base = (wave * 8 + i) * 512;
            gload_lds16(Bg1 + base + lane * 8, &Bs[1][base]);
        }
#pragma unroll
        for (int nt = 0; nt < 4; nt++) {
            int row = wn * 64 + nt * 16 + l16;
            bf16x8 b4[4];
#pragma unroll
            for (int ks = 0; ks < 4; ks++)
                b4[ks] = *(const bf16x8*)(&Bs[0][row * 128 + (((ks * 4 + quad) ^ (row & 15)) << 3)]);
#pragma unroll
            for (int mt = 0; mt < 4; mt++) {
                f32x4 c = {0.f, 0.f, 0.f, 0.f};
#pragma unroll
                for (int ks = 0; ks < 4; ks++)
                    c = __builtin_amdgcn_mfma_f32_16x16x32_bf16(a[mt][ks], b4[ks], c, 0, 0, 0);
                acc[mt][nt] = c;
            }
        }
#pragma unroll
        for (int mt = 0; mt < 4; mt++) {
#pragma unroll
            for (int nt = 0; nt < 4; nt++) {
                int w = __builtin_amdgcn_cvt_pk_fp8_f32(acc[mt][nt][0], acc[mt][nt][1], 0, false);
                w = __builtin_amdgcn_cvt_pk_fp8_f32(acc[mt][nt][2], acc[mt][nt][3], w, true);
                int col = wn * 64 + nt * 16 + l16;
#pragma unroll
                for (int r = 0; r < 4; r++)
                    escr[(wm * 64 + mt * 16 + quad * 4 + r) * 144 + col] = (char)(w >> (8 * r));
            }
        }
        __syncthreads();
        const int f = threadIdx.x;
        int row = f >> 1;
        int t_in = (bx & 7) * 128 + row;
        size_t rowbase = ((size_t)((b_ * Hn + h_) * Tn + t_in)) * 128;
#pragma unroll
        for (int i = 0; i < 4; i++) {
            int c = (f & 1) * 4 + i;
            int4 v = *(const int4*)(escr + row * 144 + c * 16);
            *(int4*)(Q + rowbase + c * 16) = v;
        }
    }

    // ================= K =================
    {
#pragma unroll
        for (int i = 0; i < 8; i++) {
            int base = (wave * 8 + i) * 512;
            gload_lds16(Bg2 + base + lane * 8, &Bs[2][base]);
        }
#pragma unroll
        for (int nt = 0; nt < 4; nt++) {
            int row = wn * 64 + nt * 16 + l16;
            bf16x8 b4[4];
#pragma unroll
            for (int ks = 0; ks < 4; ks++)
                b4[ks] = *(const bf16x8*)(&Bs[1][row * 128 + (((ks * 4 + quad) ^ (row & 15)) << 3)]);
#pragma unroll
            for (int mt = 0; mt < 4; mt++) {
                f32x4 c = {0.f, 0.f, 0.f, 0.f};
#pragma unroll
                for (int ks = 0; ks < 4; ks++)
                    c = __builtin_amdgcn_mfma_f32_16x16x32_bf16(a[mt][ks], b4[ks], c, 0, 0, 0);
                acc[mt][nt] = c;
            }
        }
        __syncthreads();
#pragma unroll
        for (int mt = 0; mt < 4; mt++) {
#pragma unroll
            for (int nt = 0; nt < 4; nt++) {
                int w = __builtin_amdgcn_cvt_pk_fp8_f32(acc[mt][nt][0], acc[mt][nt][1], 0, false);
                w = __builtin_amdgcn_cvt_pk_fp8_f32(acc[mt][nt][2], acc[mt][nt][3], w, true);
                int col = wn * 64 + nt * 16 + l16;
#pragma unroll
                for (int r = 0; r < 4; r++)
                    escr[(wm * 64 + mt * 16 + quad * 4 + r) * 144 + col] = (char)(w >> (8 * r));
            }
        }
        __syncthreads();
        const int f = threadIdx.x;
        int row = f >> 1;
        int t_in = (bx & 7) * 128 + row;
        size_t rowbase = ((size_t)((b_ * Hn + h_) * Tn + t_in)) * 128;
#pragma unroll
        for (int i = 0; i < 4; i++) {
            int c = (f & 1) * 4 + i;
            int4 v = *(const int4*)(escr + row * 144 + c * 16);
            int cc = c ^ (row & 7);
            *(int4*)(K + rowbase + cc * 16) = v;
        }
    }

    // ================= V =================
    {
#pragma unroll
        for (int nt = 0; nt < 4; nt++) {
            int row = wn * 64 + nt * 16 + l16;
            bf16x8 b4[4];
#pragma unroll
            for (int ks = 0; ks < 4; ks++)
                b4[ks] = *(const bf16x8*)(&Bs[2][row * 128 + (((ks * 4 + quad) ^ (row & 15)) << 3)]);
#pragma unroll
            for (int mt = 0; mt < 4; mt++) {
                f32x4 c = {0.f, 0.f, 0.f, 0.f};
#pragma unroll
                for (int ks = 0; ks < 4; ks++)
                    c = __builtin_amdgcn_mfma_f32_16x16x32_bf16(a[mt][ks], b4[ks], c, 0, 0, 0);
                acc[mt][nt] = c;
            }
        }
#pragma unroll
        for (int mt = 0; mt < 4; mt++) {
            int m_base = bx * 128 + wm * 64 + mt * 16 + quad * 4;
            int t0 = m_base & 1023;
#pragma unroll
            for (int nt = 0; nt < 4; nt++) {
                int e_ = wn * 64 + nt * 16 + l16;
                int kt_ = t0 >> 6, tc0 = t0 & 63;
                size_t off = ((((size_t)(b_ * Hn + h_) * 16 + kt_) * 128 + e_) << 6)
                           + ((((tc0 >> 3) ^ (e_ & 7)) << 3) | (tc0 & 7));
                ushort4 v4;
                v4.x = f2bf(acc[mt][nt][0]); v4.y = f2bf(acc[mt][nt][1]);
                v4.z = f2bf(acc[mt][nt][2]); v4.w = f2bf(acc[mt][nt][3]);
                *(ushort4*)(Vt + off) = v4;
            }
        }
    }
}

// ---------------- flash attention, 128-row q-tiles + fused output projection ----------------
// grid 512: id<256 -> qb=id&7, else qb=7-(id&7); bh=(id>>3)&63. Co-resident pairs sum
// to 18 iterations. Each wave owns 32 q-rows as 2 subtiles sharing K/V fragments;
// both subtiles share one causal bound wkmax=(q0w+31)>>6 (waves 0,1 skip last tile).
__global__ __launch_bounds__(256, 2) void attn_kernel(
    const char* __restrict__ Q,               // fp8 [64][1024][128] plain
    const char* __restrict__ K,               // fp8 [64][1024][128] chunk swizzle c^(t&7)
    const unsigned short* __restrict__ Vt,    // bf16 [64][16][128][64] tiled+swizzled
    const unsigned long long* __restrict__ mbits, // [16][1024] transposed
    const unsigned short* __restrict__ wuF,   // [((h*4+ks)*8+nt)*64+lane][8]
    float* __restrict__ out)                  // [8192][128] fp32, bias-preset
{
    const int id   = blockIdx.x;
    const int qb   = (id & 7) ^ (7 * ((id >> 8) & 1));
    const int bh   = (id >> 3) & 63;
    const int wave = threadIdx.x >> 6;
    const int lane = threadIdx.x & 63;
    const int l16  = lane & 15;
    const int quad = lane >> 4;

    __shared__ __align__(16) char kbuf[2][64 * 128];            // 8 KB each
    __shared__ __align__(16) unsigned short vbuf[2][128 * 64];  // 16 KB each

    const char* Qb = Q  + (size_t)bh * Tn * Dn;
    const char* Kb = K  + (size_t)bh * Tn * Dn;
    const unsigned short* Vb = Vt + (size_t)bh * (16 * 128 * 64);

    const int blkkt = 2 * qb + 1;                 // block k-extent
    const int q0w   = qb * 128 + wave * 32;       // wave's first row
    const int q0s[2] = { q0w, q0w + 16 };
    const int wkmax = (q0w + 31) >> 6;            // both subtiles' causal bound

    long qf[2][4];
#pragma unroll
    for (int st = 0; st < 2; st++)
#pragma unroll
        for (int ks = 0; ks < 4; ks++)
            qf[st][ks] = *(const long*)(Qb + (size_t)(q0s[st] + l16) * 128 + ks * 32 + quad * 8);

    bf16x8 ones;
#pragma unroll
    for (int j = 0; j < 8; j++) ones[j] = (short)0x3F80;

    f32x4 o[2][8];
#pragma unroll
    for (int st = 0; st < 2; st++)
#pragma unroll
        for (int et = 0; et < 8; et++) o[st][et] = (f32x4){0.f, 0.f, 0.f, 0.f};
    f32x4 lacc[2];
    lacc[0] = (f32x4){0.f, 0.f, 0.f, 0.f};
    lacc[1] = (f32x4){0.f, 0.f, 0.f, 0.f};

    const float SL = 0.12752041570284543f;  // 1/sqrt(128) * log2(e)

    const int idx0 = (l16 << 2) + ((quad & 1) << 7);
    const int idx1 = idx0 + 64;
    const bool hiQ = (quad >> 1) != 0;

    // prologue staging
#pragma unroll
    for (int i = 0; i < 2; i++) {
        int base = (wave * 2 + i) * 1024;
        gload_lds16b(Kb + base + lane * 16, &kbuf[0][base]);
    }
#pragma unroll
    for (int i = 0; i < 4; i++) {
        int base = (wave * 4 + i) * 512;
        gload_lds16(Vb + base + lane * 8, &vbuf[0][base]);
    }

    for (int kt = 0; kt <= blkkt; kt++) {
        const int cur = kt & 1;
        __syncthreads();

        if (kt < blkkt) {
            const char* Kg = Kb + (kt + 1) * (64 * 128);
            const unsigned short* Vg = Vb + (kt + 1) * (128 * 64);
#pragma unroll
            for (int i = 0; i < 2; i++) {
                int base = (wave * 2 + i) * 1024;
                gload_lds16b(Kg + base + lane * 16, &kbuf[cur ^ 1][base]);
            }
#pragma unroll
            for (int i = 0; i < 4; i++) {
                int base = (wave * 4 + i) * 512;
                gload_lds16(Vg + base + lane * 8, &vbuf[cur ^ 1][base]);
            }
        }

        if (kt <= wkmax) {
            unsigned long long mw[2];
            mw[0] = mbits[kt * Tn + q0s[0] + l16];
            mw[1] = mbits[kt * Tn + q0s[1] + l16];

            // S^T = K·Q^T (fp8), K-fragments shared by both subtiles
            f32x4 s[2][4];
#pragma unroll
            for (int nt = 0; nt < 4; nt++) {
                int row = nt * 16 + l16;
                long a4[4];
#pragma unroll
                for (int ks = 0; ks < 4; ks++) {
                    int c = ks * 2 + (quad >> 1);
                    a4[ks] = *(const long*)(&kbuf[cur][row * 128 + (((c ^ (row & 7)) << 4) | ((quad & 1) << 3))]);
                }
#pragma unroll
                for (int st = 0; st < 2; st++) {
                    f32x4 c = {0.f, 0.f, 0.f, 0.f};
#pragma unroll
                    for (int ks = 0; ks < 4; ks++)
                        c = __builtin_amdgcn_mfma_f32_16x16x32_fp8_fp8(a4[ks], qf[st][ks], c, 0, 0, 0);
                    s[st][nt] = c;
                }
            }

            // p = live ? exp2(s*SL) : 0 -> bf16 pairs -> bpermute A-layout
            const int kc0 = kt * 64;
            bf16x8 pf[2][2];
#pragma unroll
            for (int st = 0; st < 2; st++) {
                const int qglob = q0s[st] + l16;
                int w[4][2];
#pragma unroll
                for (int nt = 0; nt < 4; nt++) {
                    float pv[4];
#pragma unroll
                    for (int r = 0; r < 4; r++) {
                        int bit = nt * 16 + quad * 4 + r;
                        bool live = ((mw[st] >> bit) & 1ULL) && (kc0 + bit <= qglob);
                        pv[r] = live ? __builtin_amdgcn_exp2f(s[st][nt][r] * SL) : 0.f;
                    }
                    w[nt][0] = pack_bf16_trunc(pv[0], pv[1]);
                    w[nt][1] = pack_bf16_trunc(pv[2], pv[3]);
                }
#pragma unroll
                for (int k2 = 0; k2 < 2; k2++) {
                    union { int i[4]; bf16x8 v; } u;
#pragma unroll
                    for (int d = 0; d < 4; d++) {
                        int idx = (d < 2) ? idx0 : idx1;
                        int va = __builtin_amdgcn_ds_bpermute(idx, w[2 * k2][d & 1]);
                        int vb = __builtin_amdgcn_ds_bpermute(idx, w[2 * k2 + 1][d & 1]);
                        u.i[d] = hiQ ? vb : va;
                    }
                    pf[st][k2] = u.v;
                }
            }

#pragma unroll
            for (int st = 0; st < 2; st++)
#pragma unroll
                for (int k2 = 0; k2 < 2; k2++)
                    lacc[st] = __builtin_amdgcn_mfma_f32_16x16x32_bf16(pf[st][k2], ones, lacc[st], 0, 0, 0);

            // O += P V, V-fragments shared by both subtiles
#pragma unroll
            for (int et = 0; et < 8; et++) {
                int row = et * 16 + l16;
#pragma unroll
                for (int k2 = 0; k2 < 2; k2++) {
                    bf16x8 b = *(const bf16x8*)(&vbuf[cur][row * 64 + (((k2 * 4 + quad) ^ (l16 & 7)) << 3)]);
                    o[0][et] = __builtin_amdgcn_mfma_f32_16x16x32_bf16(pf[0][k2], b, o[0][et], 0, 0, 0);
                    o[1][et] = __builtin_amdgcn_mfma_f32_16x16x32_bf16(pf[1][k2], b, o[1][et], 0, 0, 0);
                }
            }
        }
    }

    // phase 2: degenerate rows (l == 0) attend uniformly over all mask==0 keys
    __syncthreads();
    {
        bool deg = false;
#pragma unroll
        for (int st = 0; st < 2; st++)
#pragma unroll
            for (int r = 0; r < 4; r++) deg |= (lacc[st][r] == 0.f);
        if (__ballot(deg) != 0ULL) {
            unsigned short* pb = (unsigned short*)((char*)kbuf + wave * 2304);  // 16 x 72 shorts
            unsigned short dsel[2][4];
#pragma unroll
            for (int st = 0; st < 2; st++)
#pragma unroll
                for (int r = 0; r < 4; r++)
                    dsel[st][r] = (lacc[st][r] == 0.f) ? (unsigned short)0x3F80 : (unsigned short)0;
            for (int kt = 0; kt < 16; kt++) {
#pragma unroll
                for (int st = 0; st < 2; st++) {
                    int qrow = q0s[st] + quad * 4;
                    unsigned long long mw2[4];
#pragma unroll
                    for (int r = 0; r < 4; r++) mw2[r] = mbits[kt * Tn + qrow + r];
#pragma unroll
                    for (int nt = 0; nt < 4; nt++) {
                        int bi = nt * 16 + l16;
#pragma unroll
                        for (int r = 0; r < 4; r++)
                            pb[(quad * 4 + r) * 72 + bi] = ((mw2[r] >> bi) & 1ULL) ? (unsigned short)0 : dsel[st][r];
                    }
                    bf16x8 pf[2];
#pragma unroll
                    for (int k2 = 0; k2 < 2; k2++)
                        pf[k2] = *(const bf16x8*)(&pb[l16 * 72 + k2 * 32 + quad * 8]);
#pragma unroll
                    for (int k2 = 0; k2 < 2; k2++)
                        lacc[st] = __builtin_amdgcn_mfma_f32_16x16x32_bf16(pf[k2], ones, lacc[st], 0, 0, 0);
                    const unsigned short* Vg = Vb + kt * (128 * 64);
#pragma unroll
                    for (int et = 0; et < 8; et++) {
#pragma unroll
                        for (int k2 = 0; k2 < 2; k2++) {
                            bf16x8 b = *(const bf16x8*)(Vg + (et * 16 + l16) * 64 + (((k2 * 4 + quad) ^ (l16 & 7)) << 3));
                            o[st][et] = __builtin_amdgcn_mfma_f32_16x16x32_bf16(pf[k2], b, o[st][et], 0, 0, 0);
                        }
                    }
                }
            }
        }
    }

    // ---- fused output projection epilogue (per subtile) ----
    const int b_ = bh >> 3, h_ = bh & 7;
    const unsigned short* wf = wuF + (size_t)h_ * (4 * 8 * 64 * 8);
#pragma unroll
    for (int st = 0; st < 2; st++) {
        unsigned short* tile = (unsigned short*)((char*)vbuf + wave * 4608);  // 16 rows x 144 shorts
#pragma unroll
        for (int r = 0; r < 4; r++) {
            float inv = 1.f / lacc[st][r];
            int row = quad * 4 + r;
#pragma unroll
            for (int et = 0; et < 8; et++)
                tile[row * 144 + et * 16 + l16] = f2bf(o[st][et][r] * inv);
        }

        bf16x8 a4[4];
#pragma unroll
        for (int ks = 0; ks < 4; ks++)
            a4[ks] = *(const bf16x8*)(&tile[l16 * 144 + ks * 32 + quad * 8]);

        f32x4 acc2[8];
#pragma unroll
        for (int nt = 0; nt < 8; nt++) acc2[nt] = (f32x4){0.f, 0.f, 0.f, 0.f};
#pragma unroll
        for (int ks = 0; ks < 4; ks++) {
#pragma unroll
            for (int nt = 0; nt < 8; nt++) {
                bf16x8 b = *(const bf16x8*)(wf + ((size_t)(ks * 8 + nt) * 64 + lane) * 8);
                acc2[nt] = __builtin_amdgcn_mfma_f32_16x16x32_bf16(a4[ks], b, acc2[nt], 0, 0, 0);
            }
        }

#pragma unroll
        for (int nt = 0; nt < 8; nt++) {
            int n = nt * 16 + l16;
#pragma unroll
            for (int r = 0; r < 4; r++) {
                int q = q0s[st] + quad * 4 + r;
                atomicAdd(&out[(size_t)(b_ * Tn + q) * Dn + n], acc2[nt][r]);
            }
        }
    }
}

extern "C" void kernel_launch(void* const* d_in, const int* in_sizes, int n_in,
                              void* d_out, int out_size, void* d_ws, size_t ws_size,
                              hipStream_t stream) {
    const float* x   = (const float*)d_in[0];
    const int* mask  = (const int*)d_in[1];
    const float* Wk  = (const float*)d_in[2];
    const float* Wq  = (const float*)d_in[3];
    const float* Wv  = (const float*)d_in[4];
    const float* Wu  = (const float*)d_in[5];
    const float* bu  = (const float*)d_in[6];
    float* out = (float*)d_out;

    char* ws = (char*)d_ws;
    unsigned short* xb  = (unsigned short*)ws; ws += (size_t)8192 * 128 * 2;
    unsigned short* wqB = (unsigned short*)ws; ws += (size_t)1024 * 128 * 2;
    unsigned short* wkB = (unsigned short*)ws; ws += (size_t)1024 * 128 * 2;
    unsigned short* wvB = (unsigned short*)ws; ws += (size_t)1024 * 128 * 2;
    unsigned short* wuF = (unsigned short*)ws; ws += (size_t)128 * 1024 * 2;
    char* Qf  = ws; ws += (size_t)64 * 1024 * 128;
    char* Kf  = ws; ws += (size_t)64 * 1024 * 128;
    unsigned short* Vtw = (unsigned short*)ws; ws += (size_t)64 * 1024 * 128 * 2;
    unsigned long long* mb = (unsigned long long*)ws; ws += (size_t)1024 * 16 * 8;

    prep_kernel<<<dim3(2816), 256, 0, stream>>>(x, Wq, Wk, Wv, Wu, mask, bu, out,
                                                xb, wqB, wkB, wvB, wuF, mb);
    qkv_kernel<<<dim3(64, 8), 256, 0, stream>>>(xb, wqB, wkB, wvB, Qf, Kf, Vtw);
    attn_kernel<<<dim3(512), 256, 0, stream>>>(Qf, Kf, Vtw, mb, wuF, out);
}